// Round 3
// baseline (325.081 us; speedup 1.0000x reference)
//
#include <hip/hip_runtime.h>

#define L_SEQ 2048
#define DM    1024
#define DI    2048
#define NS    16
#define DTR   64
#define CH    64   // chunks
#define CL    32   // chunk length, CH*CL == L_SEQ
#define KZ_DT 16   // split-K factor for dt1 GEMM
#define KZ_OUT 4   // split-K factor for out GEMM

typedef short bf16x8_t __attribute__((ext_vector_type(8)));
typedef float f32x4    __attribute__((ext_vector_type(4)));

__device__ __forceinline__ unsigned short f2bf(float f) {
    union { float f; unsigned int u; } v; v.f = f;
    unsigned int u = v.u;
    unsigned int r = (u + 0x7FFFu + ((u >> 16) & 1u)) >> 16;  // RNE
    return (unsigned short)r;
}

// ---------------- elementwise cast fp32 -> bf16 ----------------
__global__ void cast_bf16_kernel(const float* __restrict__ in,
                                 unsigned short* __restrict__ out, int n) {
    int i = (blockIdx.x * blockDim.x + threadIdx.x) * 4;
    if (i + 3 < n) {
        float4 v = *(const float4*)&in[i];
        ushort4 o;
        o.x = f2bf(v.x); o.y = f2bf(v.y); o.z = f2bf(v.z); o.w = f2bf(v.w);
        *(ushort4*)&out[i] = o;
    }
}

// ---------------- tiled transpose + cast: W[K][N] (f32) -> Wt[N][K] (bf16) ----------------
__global__ void tcast_kernel(const float* __restrict__ in,
                             unsigned short* __restrict__ out, int K, int N) {
    __shared__ float tile[32][33];
    int tx = threadIdx.x & 31, ty = threadIdx.x >> 5;   // 32 x 8
    int n0 = blockIdx.x * 32, k0 = blockIdx.y * 32;
    #pragma unroll
    for (int i = ty; i < 32; i += 8) {
        int k = k0 + i, n = n0 + tx;
        tile[i][tx] = (k < K && n < N) ? in[(size_t)k * N + n] : 0.f;
    }
    __syncthreads();
    #pragma unroll
    for (int i = ty; i < 32; i += 8) {
        int n = n0 + i, k = k0 + tx;
        if (n < N && k < K) out[(size_t)n * K + k] = f2bf(tile[tx][i]);
    }
}

// ---------------- bf16 MFMA GEMM with register prefetch + optional split-K ----
__global__ __launch_bounds__(256, 2)
void gemm_bf16(const unsigned short* __restrict__ A,
               const unsigned short* __restrict__ Bt,
               float* __restrict__ C,
               const float* __restrict__ bias0, const float* __restrict__ bias1,
               int bsplit, int M, int Ntot, int K, int kchunk) {
    __shared__ short As[128][40];
    __shared__ short Bs[128][40];
    const int tid  = threadIdx.x;
    const int bm   = blockIdx.y * 128, bn = blockIdx.x * 128;
    const int lane = tid & 63, wave = tid >> 6;
    const int wm   = (wave >> 1) * 64, wn = (wave & 1) * 64;
    const int quad = lane >> 4, r16 = lane & 15;

    f32x4 acc[4][4];
    #pragma unroll
    for (int i = 0; i < 4; i++)
        #pragma unroll
        for (int j = 0; j < 4; j++)
            #pragma unroll
            for (int r = 0; r < 4; r++) acc[i][j][r] = 0.f;

    const int lrow = tid >> 2;        // 0..63
    const int lcol = (tid & 3) * 8;   // 0,8,16,24
    const short* agp = (const short*)A + (size_t)(bm + lrow) * K + lcol;
    const short* bgp = (const short*)Bt + (size_t)(bn + lrow) * K + lcol;
    const size_t rstep = (size_t)64 * K;

    const int kbase  = blockIdx.z * kchunk;
    const int kiters = kchunk / 32;

    int kcur = kbase;
    bf16x8_t na0 = *(const bf16x8_t*)(agp + kcur);
    bf16x8_t na1 = *(const bf16x8_t*)(agp + rstep + kcur);
    bf16x8_t nb0 = *(const bf16x8_t*)(bgp + kcur);
    bf16x8_t nb1 = *(const bf16x8_t*)(bgp + rstep + kcur);

    for (int it = 0; it < kiters; ++it) {
        *(bf16x8_t*)&As[lrow][lcol]      = na0;
        *(bf16x8_t*)&As[lrow + 64][lcol] = na1;
        *(bf16x8_t*)&Bs[lrow][lcol]      = nb0;
        *(bf16x8_t*)&Bs[lrow + 64][lcol] = nb1;
        __syncthreads();

        int kn = (it + 1 < kiters) ? kcur + 32 : kbase;
        kcur = kn;
        na0 = *(const bf16x8_t*)(agp + kn);
        na1 = *(const bf16x8_t*)(agp + rstep + kn);
        nb0 = *(const bf16x8_t*)(bgp + kn);
        nb1 = *(const bf16x8_t*)(bgp + rstep + kn);

        bf16x8_t af[4], bfr[4];
        #pragma unroll
        for (int i = 0; i < 4; i++)
            af[i] = *(const bf16x8_t*)&As[wm + i * 16 + r16][quad * 8];
        #pragma unroll
        for (int j = 0; j < 4; j++)
            bfr[j] = *(const bf16x8_t*)&Bs[wn + j * 16 + r16][quad * 8];
        #pragma unroll
        for (int i = 0; i < 4; i++)
            #pragma unroll
            for (int j = 0; j < 4; j++)
                acc[i][j] = __builtin_amdgcn_mfma_f32_16x16x32_bf16(
                    af[i], bfr[j], acc[i][j], 0, 0, 0);
        __syncthreads();
    }

    const bool partial = (gridDim.z > 1);
    float* Cw = C + (size_t)blockIdx.z * M * Ntot;
    #pragma unroll
    for (int i = 0; i < 4; i++)
        #pragma unroll
        for (int j = 0; j < 4; j++) {
            int col = bn + wn + j * 16 + r16;
            if (col < Ntot) {
                float bv = 0.f;
                if (!partial && bias0)
                    bv = (col < bsplit) ? bias0[col] : bias1[col - bsplit];
                #pragma unroll
                for (int r = 0; r < 4; r++) {
                    int row = bm + wm + i * 16 + quad * 4 + r;
                    Cw[(size_t)row * Ntot + col] = acc[i][j][r] + bv;
                }
            }
        }
}

// ---------------- reduce split-K partials + bias (out proj) ----------------
__global__ void reduce_out_kernel(const float* __restrict__ part,
                                  const float* __restrict__ bias,
                                  float* __restrict__ out) {
    int i = (blockIdx.x * 256 + threadIdx.x) * 4;
    int col = i & (DM - 1);
    float4 s = *(const float4*)&part[i];
    #pragma unroll
    for (int z = 1; z < KZ_OUT; z++) {
        float4 p = *(const float4*)&part[(size_t)z * L_SEQ * DM + i];
        s.x += p.x; s.y += p.y; s.z += p.z; s.w += p.w;
    }
    float4 b = *(const float4*)&bias[col];
    s.x += b.x; s.y += b.y; s.z += b.z; s.w += b.w;
    *(float4*)&out[i] = s;
}

// ---------------- causal depthwise conv (k=4) + bias + silu, 8 l per thread ----
// u0 lives in the merged (L, 4096) buffer at column offset 0, row stride 4096.
__global__ void conv_silu_kernel(const float* __restrict__ u0,
                                 const float* __restrict__ cw,
                                 const float* __restrict__ cb,
                                 float* __restrict__ uf,
                                 unsigned short* __restrict__ ub) {
    int d  = blockIdx.x * 256 + threadIdx.x;
    int l0 = blockIdx.y * 8;
    float4 w = *(const float4*)&cw[d * 4];
    float bias = cb[d];
    float x0 = 0.f, x1 = 0.f, x2 = 0.f;
    if (l0 >= 3) {
        x0 = u0[(size_t)(l0 - 3) * (2 * DI) + d];
        x1 = u0[(size_t)(l0 - 2) * (2 * DI) + d];
        x2 = u0[(size_t)(l0 - 1) * (2 * DI) + d];
    }
    #pragma unroll
    for (int t = 0; t < 8; t++) {
        float x3 = u0[(size_t)(l0 + t) * (2 * DI) + d];
        float s = bias + x0 * w.x + x1 * w.y + x2 * w.z + x3 * w.w;
        float sig = 1.f / (1.f + __expf(-s));
        float v = s * sig;
        uf[(size_t)(l0 + t) * DI + d] = v;
        ub[(size_t)(l0 + t) * DI + d] = f2bf(v);
        x0 = x1; x1 = x2; x2 = x3;
    }
}

// ---------------- delta = softplus((sum_z dtl_part + dt1_b) @ dt2_w + dt2_b) ----
__global__ void delta_kernel(const float* __restrict__ dtl_part,
                             const float* __restrict__ dt1b,
                             const float* __restrict__ dt2w,
                             const float* __restrict__ dt2b,
                             float* __restrict__ delta) {
    __shared__ float dl_s[8][64];
    int tid = threadIdx.x;
    int n   = blockIdx.x * 256 + tid;
    int m0  = blockIdx.y * 8;
    for (int idx = tid; idx < 512; idx += 256) {
        int r = idx >> 6, k = idx & 63;
        float s = dt1b[k];
        #pragma unroll
        for (int z = 0; z < KZ_DT; z++)
            s += dtl_part[((size_t)z * L_SEQ + m0 + r) * DTR + k];
        dl_s[r][k] = s;
    }
    __syncthreads();
    float acc[8] = {0, 0, 0, 0, 0, 0, 0, 0};
    for (int k = 0; k < 64; k++) {
        float w = dt2w[(size_t)k * DI + n];
        #pragma unroll
        for (int r = 0; r < 8; r++) acc[r] = fmaf(dl_s[r][k], w, acc[r]);
    }
    float b = dt2b[n];
    #pragma unroll
    for (int r = 0; r < 8; r++) {
        float v = acc[r] + b;
        float sp = (v > 15.f) ? v : log1pf(__expf(v));
        delta[(size_t)(m0 + r) * DI + n] = sp;
    }
}

// ---------------- scan pass 1: thread per (d,n), 16d x 16n blocks ----------------
__global__ __launch_bounds__(256)
void scan1_kernel(const float* __restrict__ delta,
                  const float* __restrict__ uf,
                  const float* __restrict__ A_log,
                  const float* __restrict__ Bm,
                  float* __restrict__ Aprod,
                  float* __restrict__ hend) {
    __shared__ float sd[CL][16];
    __shared__ float su[CL][16];
    const int tid = threadIdx.x;
    const int n = tid & 15, dd = tid >> 4;
    const int d0 = blockIdx.x * 16;
    const int c  = blockIdx.y;
    const int l0 = c * CL;
    #pragma unroll
    for (int idx = tid; idx < CL * 16; idx += 256) {
        int t = idx >> 4, j = idx & 15;
        sd[t][j] = delta[(size_t)(l0 + t) * DI + d0 + j];
        su[t][j] = uf[(size_t)(l0 + t) * DI + d0 + j];
    }
    __syncthreads();
    const int d = d0 + dd;
    float a  = -__expf(A_log[n]);
    bool  sm = fabsf(a) < 1e-6f;
    float iA = sm ? 0.f : 1.f / a;
    float Bn = Bm[(size_t)n * DI + d];
    float h = 0.f, P = 1.f;
    #pragma unroll
    for (int t = 0; t < CL; t++) {
        float dl = sd[t][dd], ul = su[t][dd];
        float dA = dl * a;
        float ab = __expf(dA);
        float ex = sm ? dl * fmaf(0.5f, dA, 1.f) : (ab - 1.f) * iA;
        float bu = ex * Bn * ul;
        h = fmaf(ab, h, bu);
        P *= ab;
    }
    size_t base = (size_t)c * (DI * NS) + d0 * NS + tid;
    Aprod[base] = P;
    hend[base]  = h;
}

// ---------------- scan combine across chunks (64-thread blocks) ----------------
__global__ __launch_bounds__(64)
void combine_kernel(const float* __restrict__ Aprod,
                    const float* __restrict__ hend,
                    float* __restrict__ carry) {
    int t = blockIdx.x * 64 + threadIdx.x;  // series id, 0..32767
    float h = 0.f;
    for (int c = 0; c < CH; c++) {
        size_t idx = (size_t)c * (DI * NS) + t;
        carry[idx] = h;
        h = fmaf(Aprod[idx], h, hend[idx]);
    }
}

// ---------------- scan pass 2: thread per (d,n); fused gate + bf16 out ----------
// zraw lives in merged (L, 4096) buffer at column offset 2048.
__global__ __launch_bounds__(256)
void scan2_kernel(const float* __restrict__ delta,
                  const float* __restrict__ uf,
                  const float* __restrict__ ug,
                  const float* __restrict__ A_log,
                  const float* __restrict__ Bm,
                  const float* __restrict__ Cm,
                  const float* __restrict__ Dv,
                  const float* __restrict__ carry,
                  unsigned short* __restrict__ yb) {
    __shared__ float sd[CL][16];
    __shared__ float su[CL][16];
    __shared__ float sz[CL][16];
    __shared__ unsigned short sy[CL][16];
    const int tid = threadIdx.x;
    const int n = tid & 15, dd = tid >> 4;
    const int d0 = blockIdx.x * 16;
    const int c  = blockIdx.y;
    const int l0 = c * CL;
    #pragma unroll
    for (int idx = tid; idx < CL * 16; idx += 256) {
        int t = idx >> 4, j = idx & 15;
        sd[t][j] = delta[(size_t)(l0 + t) * DI + d0 + j];
        su[t][j] = uf[(size_t)(l0 + t) * DI + d0 + j];
        sz[t][j] = ug[(size_t)(l0 + t) * (2 * DI) + DI + d0 + j];
    }
    __syncthreads();
    const int d = d0 + dd;
    float a  = -__expf(A_log[n]);
    bool  sm = fabsf(a) < 1e-6f;
    float iA = sm ? 0.f : 1.f / a;
    float Bn = Bm[(size_t)n * DI + d];
    float Cn = Cm[(size_t)n * DI + d];
    float Dd = Dv[d];
    float h  = carry[(size_t)c * (DI * NS) + d0 * NS + tid];
    #pragma unroll
    for (int t = 0; t < CL; t++) {
        float dl = sd[t][dd], ul = su[t][dd];
        float dA = dl * a;
        float ab = __expf(dA);
        float ex = sm ? dl * fmaf(0.5f, dA, 1.f) : (ab - 1.f) * iA;
        float bu = ex * Bn * ul;
        h = fmaf(ab, h, bu);
        float y = h * Cn;
        y += __shfl_xor(y, 1, 64);
        y += __shfl_xor(y, 2, 64);
        y += __shfl_xor(y, 4, 64);
        y += __shfl_xor(y, 8, 64);
        if (n == 0) {
            float ytot = fmaf(Dd, ul, y);
            float z = sz[t][dd];
            float g = z / (1.f + __expf(-z));
            sy[t][dd] = f2bf(ytot * g);
        }
    }
    __syncthreads();
    // coalesced-ish store: ushort2 per thread, covers CL*16 = 512 ushorts
    {
        int t = tid >> 3, jj = (tid & 7) * 2;
        *(ushort2*)&yb[(size_t)(l0 + t) * DI + d0 + jj] = *(ushort2*)&sy[t][jj];
    }
}

extern "C" void kernel_launch(void* const* d_in, const int* in_sizes, int n_in,
                              void* d_out, int out_size, void* d_ws, size_t ws_size,
                              hipStream_t stream) {
    const float* x      = (const float*)d_in[0];
    const float* in_w   = (const float*)d_in[1];
    const float* in_b   = (const float*)d_in[2];
    const float* conv_w = (const float*)d_in[3];
    const float* conv_b = (const float*)d_in[4];
    const float* A_log  = (const float*)d_in[5];
    const float* B_mat  = (const float*)d_in[6];
    const float* C_mat  = (const float*)d_in[7];
    const float* D_vec  = (const float*)d_in[8];
    const float* gate_w = (const float*)d_in[9];
    const float* gate_b = (const float*)d_in[10];
    const float* dt1_w  = (const float*)d_in[11];
    const float* dt1_b  = (const float*)d_in[12];
    const float* dt2_w  = (const float*)d_in[13];
    const float* dt2_b  = (const float*)d_in[14];
    const float* out_w  = (const float*)d_in[15];
    const float* out_b  = (const float*)d_in[16];

    char* ws = (char*)d_ws;
    size_t off = 0;
    auto alloc = [&](size_t bytes) {
        void* p = ws + off;
        off += (bytes + 255) & ~(size_t)255;
        return p;
    };

    unsigned short* xb     = (unsigned short*)alloc((size_t)L_SEQ * DM * 2);     // 4 MB
    unsigned short* wtig   = (unsigned short*)alloc((size_t)2 * DI * DM * 2);    // 8 MB (in|gate)
    unsigned short* out_wt = (unsigned short*)alloc((size_t)DM * DI * 2);        // 4 MB
    unsigned short* dt1_wt = (unsigned short*)alloc((size_t)128 * DI * 2);       // 0.5 MB (padded rows)
    float* ug      = (float*)alloc((size_t)L_SEQ * 2 * DI * 4);                  // 32 MB (u0|zraw; later out partials)
    unsigned short* u_bf16 = (unsigned short*)alloc((size_t)L_SEQ * DI * 2);     // 8 MB
    float* u_f32   = (float*)alloc((size_t)L_SEQ * DI * 4);                      // 16 MB
    float* dtl_p   = (float*)alloc((size_t)KZ_DT * L_SEQ * DTR * 4);             // 8 MB (later y_bf16)
    float* delta   = (float*)alloc((size_t)L_SEQ * DI * 4);                      // 16 MB
    float* Aprod   = (float*)alloc((size_t)CH * DI * NS * 4);                    // 8 MB
    float* hend    = (float*)alloc((size_t)CH * DI * NS * 4);                    // 8 MB
    float* carry   = (float*)alloc((size_t)CH * DI * NS * 4);                    // 8 MB
    unsigned short* y_bf16  = (unsigned short*)dtl_p;    // alias: dtl_p dead after delta_kernel
    float* out_part         = ug;                        // alias: ug dead after scan2
    (void)ws_size; (void)in_sizes; (void)n_in; (void)out_size;

    dim3 b256(256);

    // casts / transposes
    cast_bf16_kernel<<<dim3((L_SEQ * DM) / 1024), b256, 0, stream>>>(x, xb, L_SEQ * DM);
    tcast_kernel<<<dim3(DI / 32, DM / 32), b256, 0, stream>>>(in_w, wtig, DM, DI);
    tcast_kernel<<<dim3(DI / 32, DM / 32), b256, 0, stream>>>(gate_w, wtig + (size_t)DI * DM, DM, DI);
    tcast_kernel<<<dim3(DM / 32, DI / 32), b256, 0, stream>>>(out_w, out_wt, DI, DM);
    tcast_kernel<<<dim3(DTR / 32, DI / 32), b256, 0, stream>>>(dt1_w, dt1_wt, DI, DTR);

    // merged: ug = x @ [in_w | gate_w] + [in_b | gate_b]   (M=2048, N=4096, K=1024)
    gemm_bf16<<<dim3(2 * DI / 128, L_SEQ / 128, 1), b256, 0, stream>>>(
        xb, wtig, ug, in_b, gate_b, DI, L_SEQ, 2 * DI, DM, DM);

    // u = silu(conv(u0))
    conv_silu_kernel<<<dim3(DI / 256, L_SEQ / 8), b256, 0, stream>>>(ug, conv_w, conv_b, u_f32, u_bf16);

    // dtl partials = u @ dt1_w  (split-K=16, N=64)
    gemm_bf16<<<dim3(1, L_SEQ / 128, KZ_DT), b256, 0, stream>>>(
        u_bf16, dt1_wt, dtl_p, nullptr, nullptr, 0, L_SEQ, DTR, DI, DI / KZ_DT);

    // delta = softplus((sum partials + dt1_b) @ dt2_w + dt2_b)
    delta_kernel<<<dim3(DI / 256, L_SEQ / 8), b256, 0, stream>>>(dtl_p, dt1_b, dt2_w, dt2_b, delta);

    // chunked scan (n-parallel)
    scan1_kernel<<<dim3(DI / 16, CH), b256, 0, stream>>>(delta, u_f32, A_log, B_mat, Aprod, hend);
    combine_kernel<<<dim3((DI * NS) / 64), dim3(64), 0, stream>>>(Aprod, hend, carry);
    scan2_kernel<<<dim3(DI / 16, CH), b256, 0, stream>>>(delta, u_f32, ug, A_log, B_mat, C_mat,
                                                         D_vec, carry, y_bf16);

    // out partials = y @ out_w  (split-K=4), then reduce + bias
    gemm_bf16<<<dim3(DM / 128, L_SEQ / 128, KZ_OUT), b256, 0, stream>>>(
        y_bf16, out_wt, out_part, nullptr, nullptr, 0, L_SEQ, DM, DI, DI / KZ_OUT);
    reduce_out_kernel<<<dim3((L_SEQ * DM) / 1024), b256, 0, stream>>>(out_part, out_b, (float*)d_out);
}

// Round 4
// 290.146 us; speedup vs baseline: 1.1204x; 1.1204x over previous
//
#include <hip/hip_runtime.h>

#define L_SEQ 2048
#define DM    1024
#define DI    2048
#define NS    16
#define DTR   64
#define CH    128  // chunks
#define CL    16   // chunk length, CH*CL == L_SEQ
#define KZ_DT 16   // split-K factor for dt1 GEMM
#define KZ_OUT 4   // split-K factor for out GEMM

typedef short bf16x8_t __attribute__((ext_vector_type(8)));
typedef float f32x4    __attribute__((ext_vector_type(4)));

__device__ __forceinline__ unsigned short f2bf(float f) {
    union { float f; unsigned int u; } v; v.f = f;
    unsigned int u = v.u;
    unsigned int r = (u + 0x7FFFu + ((u >> 16) & 1u)) >> 16;  // RNE
    return (unsigned short)r;
}

// ---------------- elementwise cast fp32 -> bf16 ----------------
__global__ void cast_bf16_kernel(const float* __restrict__ in,
                                 unsigned short* __restrict__ out, int n) {
    int i = (blockIdx.x * blockDim.x + threadIdx.x) * 4;
    if (i + 3 < n) {
        float4 v = *(const float4*)&in[i];
        ushort4 o;
        o.x = f2bf(v.x); o.y = f2bf(v.y); o.z = f2bf(v.z); o.w = f2bf(v.w);
        *(ushort4*)&out[i] = o;
    }
}

// ---------------- tiled transpose + cast: W[K][N] (f32) -> Wt[N][K] (bf16) ----------------
__global__ void tcast_kernel(const float* __restrict__ in,
                             unsigned short* __restrict__ out, int K, int N) {
    __shared__ float tile[32][33];
    int tx = threadIdx.x & 31, ty = threadIdx.x >> 5;   // 32 x 8
    int n0 = blockIdx.x * 32, k0 = blockIdx.y * 32;
    #pragma unroll
    for (int i = ty; i < 32; i += 8) {
        int k = k0 + i, n = n0 + tx;
        tile[i][tx] = (k < K && n < N) ? in[(size_t)k * N + n] : 0.f;
    }
    __syncthreads();
    #pragma unroll
    for (int i = ty; i < 32; i += 8) {
        int n = n0 + i, k = k0 + tx;
        if (n < N && k < K) out[(size_t)n * K + k] = f2bf(tile[tx][i]);
    }
}

// ---------------- bf16 MFMA GEMM with register prefetch + optional split-K ----
__global__ __launch_bounds__(256, 2)
void gemm_bf16(const unsigned short* __restrict__ A,
               const unsigned short* __restrict__ Bt,
               float* __restrict__ C,
               const float* __restrict__ bias0, const float* __restrict__ bias1,
               int bsplit, int M, int Ntot, int K, int kchunk) {
    __shared__ short As[128][40];
    __shared__ short Bs[128][40];
    const int tid  = threadIdx.x;
    const int bm   = blockIdx.y * 128, bn = blockIdx.x * 128;
    const int lane = tid & 63, wave = tid >> 6;
    const int wm   = (wave >> 1) * 64, wn = (wave & 1) * 64;
    const int quad = lane >> 4, r16 = lane & 15;

    f32x4 acc[4][4];
    #pragma unroll
    for (int i = 0; i < 4; i++)
        #pragma unroll
        for (int j = 0; j < 4; j++)
            #pragma unroll
            for (int r = 0; r < 4; r++) acc[i][j][r] = 0.f;

    const int lrow = tid >> 2;        // 0..63
    const int lcol = (tid & 3) * 8;   // 0,8,16,24
    const short* agp = (const short*)A + (size_t)(bm + lrow) * K + lcol;
    const short* bgp = (const short*)Bt + (size_t)(bn + lrow) * K + lcol;
    const size_t rstep = (size_t)64 * K;

    const int kbase  = blockIdx.z * kchunk;
    const int kiters = kchunk / 32;

    int kcur = kbase;
    bf16x8_t na0 = *(const bf16x8_t*)(agp + kcur);
    bf16x8_t na1 = *(const bf16x8_t*)(agp + rstep + kcur);
    bf16x8_t nb0 = *(const bf16x8_t*)(bgp + kcur);
    bf16x8_t nb1 = *(const bf16x8_t*)(bgp + rstep + kcur);

    for (int it = 0; it < kiters; ++it) {
        *(bf16x8_t*)&As[lrow][lcol]      = na0;
        *(bf16x8_t*)&As[lrow + 64][lcol] = na1;
        *(bf16x8_t*)&Bs[lrow][lcol]      = nb0;
        *(bf16x8_t*)&Bs[lrow + 64][lcol] = nb1;
        __syncthreads();

        int kn = (it + 1 < kiters) ? kcur + 32 : kbase;
        kcur = kn;
        na0 = *(const bf16x8_t*)(agp + kn);
        na1 = *(const bf16x8_t*)(agp + rstep + kn);
        nb0 = *(const bf16x8_t*)(bgp + kn);
        nb1 = *(const bf16x8_t*)(bgp + rstep + kn);

        bf16x8_t af[4], bfr[4];
        #pragma unroll
        for (int i = 0; i < 4; i++)
            af[i] = *(const bf16x8_t*)&As[wm + i * 16 + r16][quad * 8];
        #pragma unroll
        for (int j = 0; j < 4; j++)
            bfr[j] = *(const bf16x8_t*)&Bs[wn + j * 16 + r16][quad * 8];
        #pragma unroll
        for (int i = 0; i < 4; i++)
            #pragma unroll
            for (int j = 0; j < 4; j++)
                acc[i][j] = __builtin_amdgcn_mfma_f32_16x16x32_bf16(
                    af[i], bfr[j], acc[i][j], 0, 0, 0);
        __syncthreads();
    }

    const bool partial = (gridDim.z > 1);
    float* Cw = C + (size_t)blockIdx.z * M * Ntot;
    #pragma unroll
    for (int i = 0; i < 4; i++)
        #pragma unroll
        for (int j = 0; j < 4; j++) {
            int col = bn + wn + j * 16 + r16;
            if (col < Ntot) {
                float bv = 0.f;
                if (!partial && bias0)
                    bv = (col < bsplit) ? bias0[col] : bias1[col - bsplit];
                #pragma unroll
                for (int r = 0; r < 4; r++) {
                    int row = bm + wm + i * 16 + quad * 4 + r;
                    Cw[(size_t)row * Ntot + col] = acc[i][j][r] + bv;
                }
            }
        }
}

// ---------------- reduce split-K partials + bias (out proj) ----------------
__global__ void reduce_out_kernel(const float* __restrict__ part,
                                  const float* __restrict__ bias,
                                  float* __restrict__ out) {
    int i = (blockIdx.x * 256 + threadIdx.x) * 4;
    int col = i & (DM - 1);
    float4 s = *(const float4*)&part[i];
    #pragma unroll
    for (int z = 1; z < KZ_OUT; z++) {
        float4 p = *(const float4*)&part[(size_t)z * L_SEQ * DM + i];
        s.x += p.x; s.y += p.y; s.z += p.z; s.w += p.w;
    }
    float4 b = *(const float4*)&bias[col];
    s.x += b.x; s.y += b.y; s.z += b.z; s.w += b.w;
    *(float4*)&out[i] = s;
}

// ---------------- causal depthwise conv (k=4) + bias + silu, 8 l per thread ----
__global__ void conv_silu_kernel(const float* __restrict__ u0,
                                 const float* __restrict__ cw,
                                 const float* __restrict__ cb,
                                 float* __restrict__ uf,
                                 unsigned short* __restrict__ ub) {
    int d  = blockIdx.x * 256 + threadIdx.x;
    int l0 = blockIdx.y * 8;
    float4 w = *(const float4*)&cw[d * 4];
    float bias = cb[d];
    float x0 = 0.f, x1 = 0.f, x2 = 0.f;
    if (l0 >= 3) {
        x0 = u0[(size_t)(l0 - 3) * (2 * DI) + d];
        x1 = u0[(size_t)(l0 - 2) * (2 * DI) + d];
        x2 = u0[(size_t)(l0 - 1) * (2 * DI) + d];
    }
    #pragma unroll
    for (int t = 0; t < 8; t++) {
        float x3 = u0[(size_t)(l0 + t) * (2 * DI) + d];
        float s = bias + x0 * w.x + x1 * w.y + x2 * w.z + x3 * w.w;
        float sig = 1.f / (1.f + __expf(-s));
        float v = s * sig;
        uf[(size_t)(l0 + t) * DI + d] = v;
        ub[(size_t)(l0 + t) * DI + d] = f2bf(v);
        x0 = x1; x1 = x2; x2 = x3;
    }
}

// ---------------- delta = softplus((sum_z dtl_part + dt1_b) @ dt2_w + dt2_b) ----
__global__ void delta_kernel(const float* __restrict__ dtl_part,
                             const float* __restrict__ dt1b,
                             const float* __restrict__ dt2w,
                             const float* __restrict__ dt2b,
                             float* __restrict__ delta) {
    __shared__ float dl_s[8][64];
    int tid = threadIdx.x;
    int n   = blockIdx.x * 256 + tid;
    int m0  = blockIdx.y * 8;
    for (int idx = tid; idx < 512; idx += 256) {
        int r = idx >> 6, k = idx & 63;
        float s = dt1b[k];
        #pragma unroll
        for (int z = 0; z < KZ_DT; z++)
            s += dtl_part[((size_t)z * L_SEQ + m0 + r) * DTR + k];
        dl_s[r][k] = s;
    }
    __syncthreads();
    float acc[8] = {0, 0, 0, 0, 0, 0, 0, 0};
    for (int k = 0; k < 64; k++) {
        float w = dt2w[(size_t)k * DI + n];
        #pragma unroll
        for (int r = 0; r < 8; r++) acc[r] = fmaf(dl_s[r][k], w, acc[r]);
    }
    float b = dt2b[n];
    #pragma unroll
    for (int r = 0; r < 8; r++) {
        float v = acc[r] + b;
        float sp = (v > 15.f) ? v : log1pf(__expf(v));
        delta[(size_t)(m0 + r) * DI + n] = sp;
    }
}

// ---------------- scan pass 1: thread per d, 16 n in registers, prefetch ----
__global__ __launch_bounds__(64)
void scan1_kernel(const float* __restrict__ delta,
                  const float* __restrict__ uf,
                  const float* __restrict__ A_log,
                  const float* __restrict__ Bm,
                  float* __restrict__ Aprod,
                  float* __restrict__ hend) {
    const int d = blockIdx.x * 64 + threadIdx.x;
    const int c = blockIdx.y;
    const int l0 = c * CL;
    float a[NS], iA[NS], Bn[NS];
    #pragma unroll
    for (int n = 0; n < NS; n++) {
        float av = -__expf(A_log[n]);
        a[n]  = av;
        iA[n] = (fabsf(av) < 1e-6f) ? 0.f : 1.f / av;
        Bn[n] = Bm[(size_t)n * DI + d];
    }
    float h[NS], P[NS];
    #pragma unroll
    for (int n = 0; n < NS; n++) { h[n] = 0.f; P[n] = 1.f; }

    float dl = delta[(size_t)l0 * DI + d];
    float ul = uf[(size_t)l0 * DI + d];
    #pragma unroll
    for (int t = 0; t < CL; t++) {
        float dln = 0.f, uln = 0.f;
        if (t + 1 < CL) {
            dln = delta[(size_t)(l0 + t + 1) * DI + d];
            uln = uf[(size_t)(l0 + t + 1) * DI + d];
        }
        #pragma unroll
        for (int n = 0; n < NS; n++) {
            float dA = dl * a[n];
            float ab = __expf(dA);
            float ex = (fabsf(a[n]) < 1e-6f) ? dl * fmaf(0.5f, dA, 1.f)
                                             : (ab - 1.f) * iA[n];
            float bu = ex * Bn[n] * ul;
            h[n] = fmaf(ab, h[n], bu);
            P[n] *= ab;
        }
        dl = dln; ul = uln;
    }
    size_t base = ((size_t)c * DI + d) * NS;
    #pragma unroll
    for (int q = 0; q < 4; q++) {
        *(float4*)&Aprod[base + q * 4] = make_float4(P[q*4], P[q*4+1], P[q*4+2], P[q*4+3]);
        *(float4*)&hend[base + q * 4]  = make_float4(h[q*4], h[q*4+1], h[q*4+2], h[q*4+3]);
    }
}

// ---------------- scan combine across chunks (64-thread blocks) ----------------
__global__ __launch_bounds__(64)
void combine_kernel(const float* __restrict__ Aprod,
                    const float* __restrict__ hend,
                    float* __restrict__ carry) {
    int t = blockIdx.x * 64 + threadIdx.x;  // series id, 0..32767
    float h = 0.f;
    for (int c = 0; c < CH; c++) {
        size_t idx = (size_t)c * (DI * NS) + t;
        carry[idx] = h;
        h = fmaf(Aprod[idx], h, hend[idx]);
    }
}

// ---------------- scan pass 2: thread per d; fused C-dot, D, gate, bf16 store ----
__global__ __launch_bounds__(64)
void scan2_kernel(const float* __restrict__ delta,
                  const float* __restrict__ uf,
                  const float* __restrict__ ug,
                  const float* __restrict__ A_log,
                  const float* __restrict__ Bm,
                  const float* __restrict__ Cm,
                  const float* __restrict__ Dv,
                  const float* __restrict__ carry,
                  unsigned short* __restrict__ yb) {
    const int d = blockIdx.x * 64 + threadIdx.x;
    const int c = blockIdx.y;
    const int l0 = c * CL;
    float a[NS], iA[NS], Bn[NS], Cn[NS], h[NS];
    #pragma unroll
    for (int n = 0; n < NS; n++) {
        float av = -__expf(A_log[n]);
        a[n]  = av;
        iA[n] = (fabsf(av) < 1e-6f) ? 0.f : 1.f / av;
        Bn[n] = Bm[(size_t)n * DI + d];
        Cn[n] = Cm[(size_t)n * DI + d];
    }
    float Dd = Dv[d];
    size_t cbase = ((size_t)c * DI + d) * NS;
    #pragma unroll
    for (int q = 0; q < 4; q++) {
        float4 cv = *(const float4*)&carry[cbase + q * 4];
        h[q*4] = cv.x; h[q*4+1] = cv.y; h[q*4+2] = cv.z; h[q*4+3] = cv.w;
    }

    float dl = delta[(size_t)l0 * DI + d];
    float ul = uf[(size_t)l0 * DI + d];
    float zr = ug[(size_t)l0 * (2 * DI) + DI + d];
    #pragma unroll
    for (int t = 0; t < CL; t++) {
        float dln = 0.f, uln = 0.f, zrn = 0.f;
        if (t + 1 < CL) {
            dln = delta[(size_t)(l0 + t + 1) * DI + d];
            uln = uf[(size_t)(l0 + t + 1) * DI + d];
            zrn = ug[(size_t)(l0 + t + 1) * (2 * DI) + DI + d];
        }
        float y = 0.f;
        #pragma unroll
        for (int n = 0; n < NS; n++) {
            float dA = dl * a[n];
            float ab = __expf(dA);
            float ex = (fabsf(a[n]) < 1e-6f) ? dl * fmaf(0.5f, dA, 1.f)
                                             : (ab - 1.f) * iA[n];
            float bu = ex * Bn[n] * ul;
            h[n] = fmaf(ab, h[n], bu);
            y = fmaf(h[n], Cn[n], y);
        }
        float ytot = fmaf(Dd, ul, y);
        float g = zr / (1.f + __expf(-zr));
        yb[(size_t)(l0 + t) * DI + d] = f2bf(ytot * g);
        dl = dln; ul = uln; zr = zrn;
    }
}

extern "C" void kernel_launch(void* const* d_in, const int* in_sizes, int n_in,
                              void* d_out, int out_size, void* d_ws, size_t ws_size,
                              hipStream_t stream) {
    const float* x      = (const float*)d_in[0];
    const float* in_w   = (const float*)d_in[1];
    const float* in_b   = (const float*)d_in[2];
    const float* conv_w = (const float*)d_in[3];
    const float* conv_b = (const float*)d_in[4];
    const float* A_log  = (const float*)d_in[5];
    const float* B_mat  = (const float*)d_in[6];
    const float* C_mat  = (const float*)d_in[7];
    const float* D_vec  = (const float*)d_in[8];
    const float* gate_w = (const float*)d_in[9];
    const float* gate_b = (const float*)d_in[10];
    const float* dt1_w  = (const float*)d_in[11];
    const float* dt1_b  = (const float*)d_in[12];
    const float* dt2_w  = (const float*)d_in[13];
    const float* dt2_b  = (const float*)d_in[14];
    const float* out_w  = (const float*)d_in[15];
    const float* out_b  = (const float*)d_in[16];

    char* ws = (char*)d_ws;
    size_t off = 0;
    auto alloc = [&](size_t bytes) {
        void* p = ws + off;
        off += (bytes + 255) & ~(size_t)255;
        return p;
    };

    unsigned short* xb     = (unsigned short*)alloc((size_t)L_SEQ * DM * 2);     // 4 MB
    unsigned short* wtig   = (unsigned short*)alloc((size_t)2 * DI * DM * 2);    // 8 MB (in|gate)
    unsigned short* out_wt = (unsigned short*)alloc((size_t)DM * DI * 2);        // 4 MB
    unsigned short* dt1_wt = (unsigned short*)alloc((size_t)128 * DI * 2);       // 0.5 MB (padded rows)
    float* ug      = (float*)alloc((size_t)L_SEQ * 2 * DI * 4);                  // 33.5 MB (u0|zraw; later out partials)
    unsigned short* u_bf16 = (unsigned short*)alloc((size_t)L_SEQ * DI * 2);     // 8.4 MB
    float* u_f32   = (float*)alloc((size_t)L_SEQ * DI * 4);                      // 16.8 MB
    float* dtl_p   = (float*)alloc((size_t)KZ_DT * L_SEQ * DTR * 4);             // 8.4 MB (later y_bf16)
    float* delta   = (float*)alloc((size_t)L_SEQ * DI * 4);                      // 16.8 MB
    float* Aprod   = (float*)alloc((size_t)CH * DI * NS * 4);                    // 16.8 MB
    float* hend    = (float*)alloc((size_t)CH * DI * NS * 4);                    // 16.8 MB
    float* carry   = (float*)alloc((size_t)CH * DI * NS * 4);                    // 16.8 MB
    unsigned short* y_bf16  = (unsigned short*)dtl_p;    // alias: dtl_p dead after delta_kernel
    float* out_part         = ug;                        // alias: ug dead after scan2
    (void)ws_size; (void)in_sizes; (void)n_in; (void)out_size;

    dim3 b256(256);

    // casts / transposes
    cast_bf16_kernel<<<dim3((L_SEQ * DM) / 1024), b256, 0, stream>>>(x, xb, L_SEQ * DM);
    tcast_kernel<<<dim3(DI / 32, DM / 32), b256, 0, stream>>>(in_w, wtig, DM, DI);
    tcast_kernel<<<dim3(DI / 32, DM / 32), b256, 0, stream>>>(gate_w, wtig + (size_t)DI * DM, DM, DI);
    tcast_kernel<<<dim3(DM / 32, DI / 32), b256, 0, stream>>>(out_w, out_wt, DI, DM);
    tcast_kernel<<<dim3(DTR / 32, DI / 32), b256, 0, stream>>>(dt1_w, dt1_wt, DI, DTR);

    // merged: ug = x @ [in_w | gate_w] + [in_b | gate_b]   (M=2048, N=4096, K=1024)
    gemm_bf16<<<dim3(2 * DI / 128, L_SEQ / 128, 1), b256, 0, stream>>>(
        xb, wtig, ug, in_b, gate_b, DI, L_SEQ, 2 * DI, DM, DM);

    // u = silu(conv(u0))
    conv_silu_kernel<<<dim3(DI / 256, L_SEQ / 8), b256, 0, stream>>>(ug, conv_w, conv_b, u_f32, u_bf16);

    // dtl partials = u @ dt1_w  (split-K=16, N=64)
    gemm_bf16<<<dim3(1, L_SEQ / 128, KZ_DT), b256, 0, stream>>>(
        u_bf16, dt1_wt, dtl_p, nullptr, nullptr, 0, L_SEQ, DTR, DI, DI / KZ_DT);

    // delta = softplus((sum partials + dt1_b) @ dt2_w + dt2_b)
    delta_kernel<<<dim3(DI / 256, L_SEQ / 8), b256, 0, stream>>>(dtl_p, dt1_b, dt2_w, dt2_b, delta);

    // chunked scan (thread per d, registers for n)
    scan1_kernel<<<dim3(DI / 64, CH), dim3(64), 0, stream>>>(delta, u_f32, A_log, B_mat, Aprod, hend);
    combine_kernel<<<dim3((DI * NS) / 64), dim3(64), 0, stream>>>(Aprod, hend, carry);
    scan2_kernel<<<dim3(DI / 64, CH), dim3(64), 0, stream>>>(delta, u_f32, ug, A_log, B_mat, C_mat,
                                                             D_vec, carry, y_bf16);

    // out partials = y @ out_w  (split-K=4), then reduce + bias
    gemm_bf16<<<dim3(DM / 128, L_SEQ / 128, KZ_OUT), b256, 0, stream>>>(
        y_bf16, out_wt, out_part, nullptr, nullptr, 0, L_SEQ, DM, DI, DI / KZ_OUT);
    reduce_out_kernel<<<dim3((L_SEQ * DM) / 1024), b256, 0, stream>>>(out_part, out_b, (float*)d_out);
}